// Round 9
// baseline (276.288 us; speedup 1.0000x reference)
//
#include <hip/hip_runtime.h>

// ---------------------------------------------------------------------------
// ZSSR involution net, fp32. Round 9 = Round 8 + dispatch-count war.
// 15 -> 8 dispatches: t_kernel fused into e_kernel (t in LDS), border-zero
// fused into conv_in. Gap model: ~6.7us per dispatch boundary (R5/R6/R8 fit).
// Layout: x[4 g][136x136 padded px][16 ch] channel-last, 3-px zero border.
// ---------------------------------------------------------------------------

#define HH 130
#define SP 136               // padded row stride
#define PPL (SP*SP)          // 18496
#define GP (PPL*16)          // floats per group-plane
#define XBUF2 (4*GP)         // floats per feature buffer

// --- conv_in (3->64, 3x3, pad=2) + border zeroing of both ping-pong bufs ---
// Grid (80,4): bx<67 conv work, bx>=67 border zero (g-dim reused as index).
__global__ __launch_bounds__(256) void conv_in_kernel(
        const float* __restrict__ inf, const float* __restrict__ W,
        const float* __restrict__ b, float* __restrict__ x0,
        float* __restrict__ x1) {
    const int tid = threadIdx.x;
    if (blockIdx.x >= 67) {
        int idx = ((blockIdx.x - 67)*4 + blockIdx.y)*256 + tid;
        if (idx < 3192) {                      // 1596 border px * 2 buffers
            int bsel = idx & 1, e = idx >> 1;
            int r, c;
            if (e < 816) { r = e/136; c = e%136; if (r >= 3) r += 130; }
            else { int j = e-816; r = 3 + j/6; int m = j%6; c = (m<3)? m : m+130; }
            float* base = (bsel ? x1 : x0) + ((size_t)r*SP + c)*16;
            float4 z = make_float4(0.f,0.f,0.f,0.f);
            #pragma unroll
            for (int g2 = 0; g2 < 4; ++g2)
                #pragma unroll
                for (int q = 0; q < 4; ++q)
                    *(float4*)(base + (size_t)g2*GP + q*4) = z;
        }
        return;
    }
    __shared__ float wl[448];          // [16 ch][27 taps] + bias[16]
    const int g = blockIdx.y;
    for (int i = tid; i < 448; i += 256)
        wl[i] = (i < 432) ? W[g*432 + i] : b[g*16 + (i-432)];
    __syncthreads();
    int px = blockIdx.x*256 + tid;
    int pxc = px < 16900 ? px : 16899;
    int h = pxc/130, w = pxc%130;
    float xv[27];
    #pragma unroll
    for (int i = 0; i < 3; ++i)
      #pragma unroll
      for (int ky = 0; ky < 3; ++ky) {
        int y = h - 2 + ky;
        #pragma unroll
        for (int kx = 0; kx < 3; ++kx) {
            int xx = w - 2 + kx;
            float v = 0.f;
            if ((unsigned)y < 128u && (unsigned)xx < 128u)
                v = inf[i*16384 + y*128 + xx];
            xv[i*9 + ky*3 + kx] = v;
        }
      }
    float acc[16];
    #pragma unroll
    for (int c = 0; c < 16; ++c) {
        float a = wl[432 + c];
        #pragma unroll
        for (int t = 0; t < 27; ++t) a += wl[c*27 + t] * xv[t];
        acc[c] = a;
    }
    if (px < 16900) {
        float* dst = x0 + (size_t)g*GP + ((size_t)(h+3)*SP + (w+3))*16;
        #pragma unroll
        for (int q = 0; q < 4; ++q)
            *(float4*)(dst + q*4) =
                make_float4(acc[q*4], acc[q*4+1], acc[q*4+2], acc[q*4+3]);
    }
}

// --- e_kernel v7: fused t + w-gen + einsum ---------------------------------
// Grid (17,17,4): 8x8 tile, g = blockIdx.z. 256 thr = 64 px x 4 waves.
// Phase 0: stage halo (xl) and compute t (tl) - thread (px, r-quad wave).
// Phase 1: w-gen, wave = k-chunk (scalar span weights). Phase 2: einsum.
// LDS: xl[4][14][17][4] 15.2KB + wl[49][68] 13.3KB + tl[64][20] 5KB = 33.7KB
// -> 4 WGs/CU (launch_bounds 256,4 caps VGPR at 128).
__global__ __launch_bounds__(256, 4) void e_kernel(
        const float* __restrict__ x,
        const float* __restrict__ redw,   // [16][64]
        const float* __restrict__ gamma, const float* __restrict__ beta,
        const float* __restrict__ spanw,  // [4 g][49 k][16 r]
        const float* __restrict__ spanb,  // [4 g][49]
        float* __restrict__ xout)
{
    __shared__ float xl[4][14][17][4];
    __shared__ float wl[49][68];
    __shared__ float tl[64][20];
    const int tid = threadIdx.x;
    const int g = blockIdx.z;
    const int ty = blockIdx.y*8, tx = blockIdx.x*8;
    const int px = tid & 63, wv = tid >> 6;
    const int sr = px >> 3, sc = px & 7;

    // ---- stage halo: 14x14 px, 4 quads each (group g's 16 ch) ----
    for (int i = tid; i < 784; i += 256) {
        int q = i & 3, p = i >> 2;
        int r = p / 14, c = p % 14;
        int gr = ty + r, gc = tx + c;
        gr = gr < SP ? gr : SP-1;          // clamp lands in zero border
        gc = gc < SP ? gc : SP-1;
        float4 v = *(const float4*)(x + (size_t)g*GP
                                    + ((size_t)gr*SP + gc)*16 + q*4);
        *(float4*)&xl[q][r][c][0] = v;
    }

    // ---- t-phase: thread (px, wave wv) computes t[px][4wv..4wv+3] ----
    const int hh = min(ty + sr, HH-1), ww = min(tx + sc, HH-1);
    {
        const float* xb = x + ((size_t)(hh+3)*SP + (ww+3))*16;
        const float* rw = redw + wv*4*64;          // wave-uniform -> s_load
        float a0=0.f, a1=0.f, a2=0.f, a3=0.f;
        #pragma unroll
        for (int g2 = 0; g2 < 4; ++g2) {
            #pragma unroll
            for (int q = 0; q < 4; ++q) {
                float4 v = *(const float4*)(xb + (size_t)g2*GP + q*4);
                int c = g2*16 + q*4;
                a0 += rw[c]*v.x     + rw[c+1]*v.y   + rw[c+2]*v.z   + rw[c+3]*v.w;
                a1 += rw[64+c]*v.x  + rw[65+c]*v.y  + rw[66+c]*v.z  + rw[67+c]*v.w;
                a2 += rw[128+c]*v.x + rw[129+c]*v.y + rw[130+c]*v.z + rw[131+c]*v.w;
                a3 += rw[192+c]*v.x + rw[193+c]*v.y + rw[194+c]*v.z + rw[195+c]*v.w;
            }
        }
        int r0 = wv*4;
        float4 t4;
        t4.x = fmaxf(gamma[r0+0]*a0 + beta[r0+0], 0.f);
        t4.y = fmaxf(gamma[r0+1]*a1 + beta[r0+1], 0.f);
        t4.z = fmaxf(gamma[r0+2]*a2 + beta[r0+2], 0.f);
        t4.w = fmaxf(gamma[r0+3]*a3 + beta[r0+3], 0.f);
        *(float4*)&tl[px][r0] = t4;
    }
    __syncthreads();

    // ---- w-gen: lane = pixel, wave = k-chunk (13/12/12/12) ----
    {
        float t16[16];
        #pragma unroll
        for (int q = 0; q < 4; ++q) {
            float4 v = *(const float4*)&tl[px][q*4];
            t16[q*4]=v.x; t16[q*4+1]=v.y; t16[q*4+2]=v.z; t16[q*4+3]=v.w;
        }
        const float* sw = spanw + g*784;   // k,r loop-uniform -> s_load
        const float* sb = spanb + g*49;
        const int k0 = wv ? (wv*12 + 1) : 0;
        #pragma unroll
        for (int j = 0; j < 12; ++j) {
            int k = k0 + j;
            float a = sb[k];
            #pragma unroll
            for (int r = 0; r < 16; ++r) a += sw[k*16 + r] * t16[r];
            wl[k][px] = a;
        }
        if (wv == 0) {
            float a = sb[12];
            #pragma unroll
            for (int r = 0; r < 16; ++r) a += sw[12*16 + r] * t16[r];
            wl[12][px] = a;
        }
    }
    __syncthreads();

    // ---- einsum: 49 taps x 4 channels (wave's quad), all LDS ----
    const int cq = wv;
    float4 acc = make_float4(0.f, 0.f, 0.f, 0.f);
    #pragma unroll
    for (int i = 0; i < 7; ++i)
        #pragma unroll
        for (int j = 0; j < 7; ++j) {
            float4 xv = *(const float4*)&xl[cq][sr + i][sc + j][0];
            float wk = wl[i*7 + j][px];
            acc.x += wk*xv.x; acc.y += wk*xv.y;
            acc.z += wk*xv.z; acc.w += wk*xv.w;
        }

    const int h = ty + sr, w = tx + sc;
    if (h < HH && w < HH) {
        float4 o;
        o.x = fmaxf(acc.x, 0.f); o.y = fmaxf(acc.y, 0.f);
        o.z = fmaxf(acc.z, 0.f); o.w = fmaxf(acc.w, 0.f);
        *(float4*)(xout + (size_t)g*GP
                   + ((size_t)(h+3)*SP + (w+3))*16 + cq*4) = o;
    }
}

// --- conv_out (64->12, 3x3 valid) + PixelShuffle(2) ------------------------
__global__ __launch_bounds__(256) void conv_out_ps_kernel(
        const float* __restrict__ x, const float* __restrict__ W,
        const float* __restrict__ b, float* __restrict__ out)
{
    __shared__ float xh[64*120];   // [c][10 r][12 cl]
    __shared__ float wl[6912];     // 12*64*9
    const int tid = threadIdx.x;
    const int ty = blockIdx.y*8, tx = blockIdx.x*8;

    for (int idx = tid; idx < 6912; idx += 256) wl[idx] = W[idx];
    for (int idx = tid; idx < 1600; idx += 256) {
        int g = idx/400, rem = idx%400;
        int p100 = rem>>2, q = rem&3;
        int r = p100/10, cl = p100%10;
        float4 v = *(const float4*)(x + (size_t)g*GP
                     + ((size_t)(ty + r + 3)*SP + tx + cl + 3)*16 + q*4);
        int c0 = g*16 + q*4;
        xh[(c0+0)*120 + r*12 + cl] = v.x;
        xh[(c0+1)*120 + r*12 + cl] = v.y;
        xh[(c0+2)*120 + r*12 + cl] = v.z;
        xh[(c0+3)*120 + r*12 + cl] = v.w;
    }
    __syncthreads();

    const int wave = __builtin_amdgcn_readfirstlane(tid >> 6);
    const int lane = tid & 63;
    const int s = lane >> 2, cq = lane & 3;
    const int sr = s >> 1, pc0 = (s & 1)*4;
    float acc[3][4] = {};

    for (int c = cq*16; c < cq*16 + 16; ++c) {
        #pragma unroll
        for (int ky = 0; ky < 3; ++ky) {
            const float* xb = &xh[c*120 + (sr + ky)*12 + pc0];
            float4 xa = *(const float4*)xb;
            float2 xm = *(const float2*)(xb + 4);
            float xr[6] = {xa.x, xa.y, xa.z, xa.w, xm.x, xm.y};
            #pragma unroll
            for (int oj = 0; oj < 3; ++oj) {
                const float* wp = &wl[((wave*3 + oj)*64 + c)*9 + ky*3];
                #pragma unroll
                for (int kx = 0; kx < 3; ++kx) {
                    float wv = wp[kx];
                    #pragma unroll
                    for (int q = 0; q < 4; ++q)
                        acc[oj][q] += wv * xr[kx + q];
                }
            }
        }
    }

    #pragma unroll
    for (int oj = 0; oj < 3; ++oj)
        #pragma unroll
        for (int q = 0; q < 4; ++q) {
            float v = acc[oj][q];
            v += __shfl_xor(v, 1, 64);
            v += __shfl_xor(v, 2, 64);
            acc[oj][q] = v;
        }

    if (cq == 0) {
        #pragma unroll
        for (int oj = 0; oj < 3; ++oj) {
            int o = wave*3 + oj;
            float bo = b[o];
            int c3 = o >> 2, r = (o >> 1) & 1, s2 = o & 1;
            int h = ty + sr;
            #pragma unroll
            for (int q = 0; q < 4; ++q) {
                int w = tx + pc0 + q;
                out[c3*65536 + (2*h + r)*256 + 2*w + s2] = acc[oj][q] + bo;
            }
        }
    }
}

// ---------------------------------------------------------------------------
extern "C" void kernel_launch(void* const* d_in, const int* in_sizes, int n_in,
                              void* d_out, int out_size, void* d_ws, size_t ws_size,
                              hipStream_t stream) {
    const float* inf   = (const float*)d_in[0];
    const float* cinw  = (const float*)d_in[1];
    const float* cinb  = (const float*)d_in[2];
    const float* redw  = (const float*)d_in[3];
    const float* gam   = (const float*)d_in[4];
    const float* bet   = (const float*)d_in[5];
    const float* spw   = (const float*)d_in[6];
    const float* spb   = (const float*)d_in[7];
    const float* cow   = (const float*)d_in[8];
    const float* cob   = (const float*)d_in[9];

    float* ws = (float*)d_ws;
    float* x0 = ws;
    float* x1 = ws + XBUF2;

    conv_in_kernel<<<dim3(80, 4), 256, 0, stream>>>(inf, cinw, cinb, x0, x1);

    float* cur = x0; float* nxt = x1;
    for (int l = 0; l < 6; ++l) {
        e_kernel<<<dim3(17, 17, 4), 256, 0, stream>>>(
            cur, redw + l*1024, gam + l*16, bet + l*16,
            spw + l*3136, spb + l*196, nxt);
        float* t = cur; cur = nxt; nxt = t;
    }

    conv_out_ps_kernel<<<dim3(16, 16), 256, 0, stream>>>(
        cur, cow, cob, (float*)d_out);
}

// Round 10
// 212.568 us; speedup vs baseline: 1.2998x; 1.2998x over previous
//
#include <hip/hip_runtime.h>

// ---------------------------------------------------------------------------
// ZSSR involution net, fp32. Round 10 = Round 8 structure + XCD-locality.
// Theory: per-XCD L2s are not coherent; consumers of the previous kernel's
// output miss to L3/HBM (~900cyc) when WG placement is random. Fix: 1-D grids
// with tile-band <-> XCD-residue (wid%8) fixed across ALL kernels/layers, so
// producer and consumer of each spatial region share an XCD L2.
// Layout: x[4 g][136x136 padded px][16 ch] channel-last, 3-px zero border.
// Bands: tile T = by*17+bx (0..288); band k = tiles [k*37, k*37+36].
// ---------------------------------------------------------------------------

#define HH 130
#define SP 136               // padded row stride
#define PPL (SP*SP)          // 18496
#define GP (PPL*16)          // floats per group-plane
#define XBUF2 (4*GP)         // floats per feature buffer
#define OFF_TF (2*XBUF2)     // t-field: 16900*16 floats [px][16]

// --- conv_in (3->64, 3x3, pad=2) + border zeroing of both ping-pong bufs ---
__global__ __launch_bounds__(256) void conv_in_kernel(
        const float* __restrict__ inf, const float* __restrict__ W,
        const float* __restrict__ b, float* __restrict__ x0,
        float* __restrict__ x1) {
    const int tid = threadIdx.x;
    if (blockIdx.x >= 67) {
        int idx = ((blockIdx.x - 67)*4 + blockIdx.y)*256 + tid;
        if (idx < 3192) {                      // 1596 border px * 2 buffers
            int bsel = idx & 1, e = idx >> 1;
            int r, c;
            if (e < 816) { r = e/136; c = e%136; if (r >= 3) r += 130; }
            else { int j = e-816; r = 3 + j/6; int m = j%6; c = (m<3)? m : m+130; }
            float* base = (bsel ? x1 : x0) + ((size_t)r*SP + c)*16;
            float4 z = make_float4(0.f,0.f,0.f,0.f);
            #pragma unroll
            for (int g2 = 0; g2 < 4; ++g2)
                #pragma unroll
                for (int q = 0; q < 4; ++q)
                    *(float4*)(base + (size_t)g2*GP + q*4) = z;
        }
        return;
    }
    __shared__ float wl[448];          // [16 ch][27 taps] + bias[16]
    const int g = blockIdx.y;
    for (int i = tid; i < 448; i += 256)
        wl[i] = (i < 432) ? W[g*432 + i] : b[g*16 + (i-432)];
    __syncthreads();
    int px = blockIdx.x*256 + tid;
    int pxc = px < 16900 ? px : 16899;
    int h = pxc/130, w = pxc%130;
    float xv[27];
    #pragma unroll
    for (int i = 0; i < 3; ++i)
      #pragma unroll
      for (int ky = 0; ky < 3; ++ky) {
        int y = h - 2 + ky;
        #pragma unroll
        for (int kx = 0; kx < 3; ++kx) {
            int xx = w - 2 + kx;
            float v = 0.f;
            if ((unsigned)y < 128u && (unsigned)xx < 128u)
                v = inf[i*16384 + y*128 + xx];
            xv[i*9 + ky*3 + kx] = v;
        }
      }
    float acc[16];
    #pragma unroll
    for (int c = 0; c < 16; ++c) {
        float a = wl[432 + c];
        #pragma unroll
        for (int t = 0; t < 27; ++t) a += wl[c*27 + t] * xv[t];
        acc[c] = a;
    }
    if (px < 16900) {
        float* dst = x0 + (size_t)g*GP + ((size_t)(h+3)*SP + (w+3))*16;
        #pragma unroll
        for (int q = 0; q < 4; ++q)
            *(float4*)(dst + q*4) =
                make_float4(acc[q*4], acc[q*4+1], acc[q*4+2], acc[q*4+3]);
    }
}

// --- t_kernel: tile-shaped (8x8 px), band-swizzled -------------------------
// grid 296: wid&7 = band (XCD), wid>>3 = slot in band. 256 thr = 64px x 4 rq.
__global__ __launch_bounds__(256) void t_kernel(
        const float* __restrict__ x, float* __restrict__ tf,
        const float* __restrict__ redw,   // [16][64]
        const float* __restrict__ gamma, const float* __restrict__ beta)
{
    const int wid = blockIdx.x;
    const int T = (wid & 7)*37 + (wid >> 3);
    if (T >= 289) return;
    const int ty = (T/17)*8, tx = (T%17)*8;
    const int tid = threadIdx.x;
    const int lane = tid & 63;
    const int rq = __builtin_amdgcn_readfirstlane(tid >> 6);
    const int h = ty + (lane >> 3), w = tx + (lane & 7);
    const int hc = h < HH ? h : HH-1, wc = w < HH ? w : HH-1;

    const float* xb = x + ((size_t)(hc+3)*SP + (wc+3))*16;
    const float* rw = redw + rq*4*64;
    float a0=0.f, a1=0.f, a2=0.f, a3=0.f;
    #pragma unroll
    for (int g2 = 0; g2 < 4; ++g2) {
        #pragma unroll
        for (int q = 0; q < 4; ++q) {
            float4 v = *(const float4*)(xb + (size_t)g2*GP + q*4);
            int c = g2*16 + q*4;
            a0 += rw[c]*v.x     + rw[c+1]*v.y   + rw[c+2]*v.z   + rw[c+3]*v.w;
            a1 += rw[64+c]*v.x  + rw[65+c]*v.y  + rw[66+c]*v.z  + rw[67+c]*v.w;
            a2 += rw[128+c]*v.x + rw[129+c]*v.y + rw[130+c]*v.z + rw[131+c]*v.w;
            a3 += rw[192+c]*v.x + rw[193+c]*v.y + rw[194+c]*v.z + rw[195+c]*v.w;
        }
    }
    if (h < HH && w < HH) {
        int r0 = rq*4;
        float4 t4;
        t4.x = fmaxf(gamma[r0+0]*a0 + beta[r0+0], 0.f);
        t4.y = fmaxf(gamma[r0+1]*a1 + beta[r0+1], 0.f);
        t4.z = fmaxf(gamma[r0+2]*a2 + beta[r0+2], 0.f);
        t4.w = fmaxf(gamma[r0+3]*a3 + beta[r0+3], 0.f);
        *(float4*)(tf + ((size_t)h*HH + w)*16 + r0) = t4;
    }
}

// --- e_kernel v8 = R8's v6 + band swizzle + scalar-uniform wv --------------
// grid 1184: wid&7 = band, slot = wid>>3; T = band*37 + (slot>>2), g = slot&3.
// LDS: xl[4][14][17][4] 15.2KB + wl[49][68] 13.3KB = 28.5KB.
__global__ __launch_bounds__(256, 4) void e_kernel(
        const float* __restrict__ x, const float* __restrict__ tf,
        const float* __restrict__ spanw,  // [4 g][49 k][16 r]
        const float* __restrict__ spanb,  // [4 g][49]
        float* __restrict__ xout)
{
    __shared__ float xl[4][14][17][4];
    __shared__ float wl[49][68];
    const int wid = blockIdx.x;
    const int slot = wid >> 3;
    const int T = (wid & 7)*37 + (slot >> 2);
    if (T >= 289) return;
    const int g = slot & 3;
    const int ty = (T/17)*8, tx = (T%17)*8;
    const int tid = threadIdx.x;
    const int px = tid & 63;
    const int wv = __builtin_amdgcn_readfirstlane(tid >> 6);
    const int sr = px >> 3, sc = px & 7;

    // ---- stage halo: 14x14 px, 4 quads each (group g's 16 ch) ----
    for (int i = tid; i < 784; i += 256) {
        int q = i & 3, p = i >> 2;
        int r = p / 14, c = p % 14;
        int gr = ty + r, gc = tx + c;
        gr = gr < SP ? gr : SP-1;          // clamp lands in zero border
        gc = gc < SP ? gc : SP-1;
        float4 v = *(const float4*)(x + (size_t)g*GP
                                    + ((size_t)gr*SP + gc)*16 + q*4);
        *(float4*)&xl[q][r][c][0] = v;
    }

    // ---- w-gen: lane = pixel, wave = k-chunk (13/12/12/12) ----
    {
        const int hh = min(ty + sr, HH-1), ww = min(tx + sc, HH-1);
        const float* tp = tf + ((size_t)hh*HH + ww)*16;
        float t16[16];
        #pragma unroll
        for (int q = 0; q < 4; ++q) {
            float4 v = *(const float4*)(tp + q*4);
            t16[q*4]=v.x; t16[q*4+1]=v.y; t16[q*4+2]=v.z; t16[q*4+3]=v.w;
        }
        const float* sw = spanw + g*784;   // k,r wave-uniform -> s_load
        const float* sb = spanb + g*49;
        const int k0 = wv ? (wv*12 + 1) : 0;
        #pragma unroll
        for (int j = 0; j < 12; ++j) {
            int k = k0 + j;
            float a = sb[k];
            #pragma unroll
            for (int r = 0; r < 16; ++r) a += sw[k*16 + r] * t16[r];
            wl[k][px] = a;
        }
        if (wv == 0) {
            float a = sb[12];
            #pragma unroll
            for (int r = 0; r < 16; ++r) a += sw[12*16 + r] * t16[r];
            wl[12][px] = a;
        }
    }
    __syncthreads();

    // ---- einsum: 49 taps x 4 channels (wave's quad), all LDS ----
    const int cq = wv;
    float4 acc = make_float4(0.f, 0.f, 0.f, 0.f);
    #pragma unroll
    for (int i = 0; i < 7; ++i)
        #pragma unroll
        for (int j = 0; j < 7; ++j) {
            float4 xv = *(const float4*)&xl[cq][sr + i][sc + j][0];
            float wk = wl[i*7 + j][px];
            acc.x += wk*xv.x; acc.y += wk*xv.y;
            acc.z += wk*xv.z; acc.w += wk*xv.w;
        }

    const int h = ty + sr, w = tx + sc;
    if (h < HH && w < HH) {
        float4 o;
        o.x = fmaxf(acc.x, 0.f); o.y = fmaxf(acc.y, 0.f);
        o.z = fmaxf(acc.z, 0.f); o.w = fmaxf(acc.w, 0.f);
        *(float4*)(xout + (size_t)g*GP
                   + ((size_t)(h+3)*SP + (w+3))*16 + cq*4) = o;
    }
}

// --- conv_out (64->12, 3x3 valid) + PixelShuffle(2) ------------------------
__global__ __launch_bounds__(256) void conv_out_ps_kernel(
        const float* __restrict__ x, const float* __restrict__ W,
        const float* __restrict__ b, float* __restrict__ out)
{
    __shared__ float xh[64*120];   // [c][10 r][12 cl]
    __shared__ float wl[6912];     // 12*64*9
    const int tid = threadIdx.x;
    const int ty = blockIdx.y*8, tx = blockIdx.x*8;

    for (int idx = tid; idx < 6912; idx += 256) wl[idx] = W[idx];
    for (int idx = tid; idx < 1600; idx += 256) {
        int g = idx/400, rem = idx%400;
        int p100 = rem>>2, q = rem&3;
        int r = p100/10, cl = p100%10;
        float4 v = *(const float4*)(x + (size_t)g*GP
                     + ((size_t)(ty + r + 3)*SP + tx + cl + 3)*16 + q*4);
        int c0 = g*16 + q*4;
        xh[(c0+0)*120 + r*12 + cl] = v.x;
        xh[(c0+1)*120 + r*12 + cl] = v.y;
        xh[(c0+2)*120 + r*12 + cl] = v.z;
        xh[(c0+3)*120 + r*12 + cl] = v.w;
    }
    __syncthreads();

    const int wave = __builtin_amdgcn_readfirstlane(tid >> 6);
    const int lane = tid & 63;
    const int s = lane >> 2, cq = lane & 3;
    const int sr = s >> 1, pc0 = (s & 1)*4;
    float acc[3][4] = {};

    for (int c = cq*16; c < cq*16 + 16; ++c) {
        #pragma unroll
        for (int ky = 0; ky < 3; ++ky) {
            const float* xb = &xh[c*120 + (sr + ky)*12 + pc0];
            float4 xa = *(const float4*)xb;
            float2 xm = *(const float2*)(xb + 4);
            float xr[6] = {xa.x, xa.y, xa.z, xa.w, xm.x, xm.y};
            #pragma unroll
            for (int oj = 0; oj < 3; ++oj) {
                const float* wp = &wl[((wave*3 + oj)*64 + c)*9 + ky*3];
                #pragma unroll
                for (int kx = 0; kx < 3; ++kx) {
                    float wv = wp[kx];
                    #pragma unroll
                    for (int q = 0; q < 4; ++q)
                        acc[oj][q] += wv * xr[kx + q];
                }
            }
        }
    }

    #pragma unroll
    for (int oj = 0; oj < 3; ++oj)
        #pragma unroll
        for (int q = 0; q < 4; ++q) {
            float v = acc[oj][q];
            v += __shfl_xor(v, 1, 64);
            v += __shfl_xor(v, 2, 64);
            acc[oj][q] = v;
        }

    if (cq == 0) {
        #pragma unroll
        for (int oj = 0; oj < 3; ++oj) {
            int o = wave*3 + oj;
            float bo = b[o];
            int c3 = o >> 2, r = (o >> 1) & 1, s2 = o & 1;
            int h = ty + sr;
            #pragma unroll
            for (int q = 0; q < 4; ++q) {
                int w = tx + pc0 + q;
                out[c3*65536 + (2*h + r)*256 + 2*w + s2] = acc[oj][q] + bo;
            }
        }
    }
}

// ---------------------------------------------------------------------------
extern "C" void kernel_launch(void* const* d_in, const int* in_sizes, int n_in,
                              void* d_out, int out_size, void* d_ws, size_t ws_size,
                              hipStream_t stream) {
    const float* inf   = (const float*)d_in[0];
    const float* cinw  = (const float*)d_in[1];
    const float* cinb  = (const float*)d_in[2];
    const float* redw  = (const float*)d_in[3];
    const float* gam   = (const float*)d_in[4];
    const float* bet   = (const float*)d_in[5];
    const float* spw   = (const float*)d_in[6];
    const float* spb   = (const float*)d_in[7];
    const float* cow   = (const float*)d_in[8];
    const float* cob   = (const float*)d_in[9];

    float* ws = (float*)d_ws;
    float* x0 = ws;
    float* x1 = ws + XBUF2;
    float* tfield = ws + OFF_TF;

    conv_in_kernel<<<dim3(80, 4), 256, 0, stream>>>(inf, cinw, cinb, x0, x1);

    float* cur = x0; float* nxt = x1;
    for (int l = 0; l < 6; ++l) {
        t_kernel<<<296, 256, 0, stream>>>(
            cur, tfield, redw + l*1024, gam + l*16, bet + l*16);
        e_kernel<<<1184, 256, 0, stream>>>(
            cur, tfield, spw + l*3136, spb + l*196, nxt);
        float* t = cur; cur = nxt; nxt = t;
    }

    conv_out_ps_kernel<<<dim3(16, 16), 256, 0, stream>>>(
        cur, cow, cob, (float*)d_out);
}